// Round 1
// baseline (1345.000 us; speedup 1.0000x reference)
//
#include <hip/hip_runtime.h>
#include <hip/hip_bf16.h>
#include <math.h>

#define E_N   8192
#define K_N   16
#define HID   128
#define HEADS 8
#define HD    16
#define NRAD  64

__device__ __forceinline__ float silu_f(float x){ return x / (1.f + __expf(-x)); }
__device__ __forceinline__ float sigmoid_f(float x){ return 1.f / (1.f + __expf(-x)); }

// ---------------- Kernel A: q,k,v = ef @ {Wq,Wk,Wv} ----------------
__global__ __launch_bounds__(256) void qkv_kernel(
    const float* __restrict__ ef,
    const float* __restrict__ Wq, const float* __restrict__ Wk, const float* __restrict__ Wv,
    float* __restrict__ q, float* __restrict__ k, float* __restrict__ v)
{
  __shared__ float efl[16][128];
  const int t = threadIdx.x;
  const int base = blockIdx.x * 16;
  for (int idx = t; idx < 16*128; idx += 256)
    efl[idx>>7][idx&127] = ef[base*128 + idx];
  __syncthreads();

  const int j = t & 127, half = t >> 7;
  float aq[8], ak[8], av[8];
  #pragma unroll
  for (int r=0;r<8;r++){ aq[r]=0.f; ak[r]=0.f; av[r]=0.f; }
  for (int i=0;i<128;i++){
    float wq = Wq[i*128+j], wk = Wk[i*128+j], wv = Wv[i*128+j];
    #pragma unroll
    for (int r=0;r<8;r++){
      float x = efl[half*8+r][i];
      aq[r] += x*wq; ak[r] += x*wk; av[r] += x*wv;
    }
  }
  #pragma unroll
  for (int r=0;r<8;r++){
    int row = base + half*8 + r;
    q[row*128+j]=aq[r]; k[row*128+j]=ak[r]; v[row*128+j]=av[r];
  }
}

// ---------------- Kernel B: gate[e][h] = sigmoid(silu(v[e,h]@Wg1+bg1)@Wg2+bg2) -------
__global__ __launch_bounds__(256) void gate_kernel(
    const float* __restrict__ v,
    const float* __restrict__ Wg1, const float* __restrict__ bg1,
    const float* __restrict__ Wg2, const float* __restrict__ bg2,
    float* __restrict__ gate)
{
  const int e = blockIdx.x;
  const int t = threadIdx.x;
  const int h = t >> 5, l = t & 31;
  float vp[16];
  #pragma unroll
  for (int i=0;i<16;i++) vp[i] = v[e*128 + h*16 + i];
  float part = 0.f;
  #pragma unroll
  for (int jj=0;jj<4;jj++){
    int j = l + jj*32;
    float a = bg1[j];
    #pragma unroll
    for (int i=0;i<16;i++) a += vp[i]*Wg1[i*128+j];
    part += silu_f(a) * Wg2[j];
  }
  #pragma unroll
  for (int off=16; off>=1; off>>=1) part += __shfl_xor(part, off, 64);
  if (l==0) gate[e*8+h] = sigmoid_f(part + bg2[0]);
}

// ---------------- Kernel C: per-src-edge fused MLP + softmax + agg + Wo + LN ---------
__global__ __launch_bounds__(256) void edge_attn_kernel(
    const float* __restrict__ ef, const float* __restrict__ coords,
    const float* __restrict__ q, const float* __restrict__ k, const float* __restrict__ v,
    const float* __restrict__ W1, const float* __restrict__ b1,
    const float* __restrict__ W2, const float* __restrict__ b2,
    const float* __restrict__ W3, const float* __restrict__ b3,
    const float* __restrict__ Wo, const float* __restrict__ bo,
    const float* __restrict__ gamma, const float* __restrict__ beta,
    const int* __restrict__ pairs, const float* __restrict__ gate,
    float* __restrict__ out_y, float* __restrict__ out_c)
{
  __shared__ float q_l[128];
  __shared__ float k_l[16][128];
  __shared__ float v_l[16][128];
  __shared__ float rb_l[16][64];
  __shared__ float dot_l[16][8];
  __shared__ float gate_l[16][8];
  __shared__ float cd_l[16][4];     // [.][3] holds dist, later reused for gate-weighted attn sum
  __shared__ float H1[16][128];
  __shared__ float sc_l[16][8];
  __shared__ float attn_l[16][8];
  __shared__ float scsum[4][8];
  __shared__ float feats[128];
  __shared__ int   dstl[16];
  __shared__ float red[4];

  const int e = blockIdx.x;
  const int t = threadIdx.x;

  if (t < 16) dstl[t] = pairs[(e*16 + t)*2 + 1];
  if (t < 128) q_l[t] = q[e*128 + t];
  __syncthreads();

  for (int idx = t; idx < 16*128; idx += 256){
    int p = idx >> 7, j = idx & 127;
    int d = dstl[p];
    k_l[p][j] = k[d*128 + j];
    v_l[p][j] = v[d*128 + j];
  }
  if (t < 16){
    int d = dstl[t];
    float cx = coords[e*3+0]-coords[d*3+0];
    float cy = coords[e*3+1]-coords[d*3+1];
    float cz = coords[e*3+2]-coords[d*3+2];
    cd_l[t][0]=cx; cd_l[t][1]=cy; cd_l[t][2]=cz;
    cd_l[t][3]=sqrtf(cx*cx+cy*cy+cz*cz);
  }
  if (t >= 128 && t < 256){
    int idx = t - 128; int p = idx>>3, h = idx&7;
    if (idx < 128) gate_l[p][h] = gate[dstl[p]*8 + h];
  }
  __syncthreads();

  // radial basis (shared across heads)
  for (int idx = t; idx < 16*64; idx += 256){
    int p = idx >> 6, i = idx & 63;
    float c = (float)i * (10.0f/63.0f);
    float z = (cd_l[p][3] - c) * (64.0f/10.0f);
    rb_l[p][i] = __expf(-z*z);
  }
  // q.k dot per (pair, head)
  if (t < 128){
    int p = t>>3, h = t&7;
    float s = 0.f;
    #pragma unroll
    for (int i=0;i<16;i++) s += q_l[h*16+i]*k_l[p][h*16+i];
    dot_l[p][h] = s;
  }
  __syncthreads();

  const int j  = t & 127;
  const int rh = t >> 7;          // 0/1 -> which pair of the sub-block
  float w3j[8];
  #pragma unroll
  for (int h=0;h<8;h++) w3j[h] = W3[j*8+h];
  const float b1j = b1[j];
  const float b2j = b2[j];

  for (int sb = 0; sb < 8; sb++){
    const int p = sb*2 + rh;
    // ---- layer 1: H1[16 rows][128] ----
    float acc[8];
    #pragma unroll
    for (int h=0;h<8;h++) acc[h] = b1j;
    // q segment (i=0..15), per-head input
    #pragma unroll
    for (int iq=0; iq<4; iq++){
      int i0 = iq*4;
      float w0=W1[(i0+0)*128+j], w1=W1[(i0+1)*128+j], w2=W1[(i0+2)*128+j], w3=W1[(i0+3)*128+j];
      #pragma unroll
      for (int h=0;h<8;h++){
        float4 xv = *reinterpret_cast<const float4*>(&q_l[h*16+i0]);
        acc[h] += xv.x*w0 + xv.y*w1 + xv.z*w2 + xv.w*w3;
      }
    }
    // k segment (i=16..31)
    #pragma unroll
    for (int iq=0; iq<4; iq++){
      int i0 = iq*4;
      float w0=W1[(16+i0+0)*128+j], w1=W1[(16+i0+1)*128+j], w2=W1[(16+i0+2)*128+j], w3=W1[(16+i0+3)*128+j];
      #pragma unroll
      for (int h=0;h<8;h++){
        float4 xv = *reinterpret_cast<const float4*>(&k_l[p][h*16+i0]);
        acc[h] += xv.x*w0 + xv.y*w1 + xv.z*w2 + xv.w*w3;
      }
    }
    // rb segment (i=32..95): head-invariant -> compute once, add to all heads
    {
      float accRB = 0.f;
      #pragma unroll
      for (int iq=0; iq<16; iq++){
        int i0 = iq*4;
        float4 xv = *reinterpret_cast<const float4*>(&rb_l[p][i0]);
        float w0=W1[(32+i0+0)*128+j], w1=W1[(32+i0+1)*128+j], w2=W1[(32+i0+2)*128+j], w3=W1[(32+i0+3)*128+j];
        accRB += xv.x*w0 + xv.y*w1 + xv.z*w2 + xv.w*w3;
      }
      #pragma unroll
      for (int h=0;h<8;h++) acc[h] += accRB;
    }
    // dot segment (i=96)
    {
      float w0 = W1[96*128+j];
      #pragma unroll
      for (int h=0;h<8;h++) acc[h] += dot_l[p][h]*w0;
    }
    #pragma unroll
    for (int h=0;h<8;h++) H1[rh*8+h][j] = silu_f(acc[h]);
    __syncthreads();

    // ---- layer 2 + score ----
    float acc2[8];
    #pragma unroll
    for (int h=0;h<8;h++) acc2[h] = b2j;
    for (int iq=0; iq<32; iq++){
      int i0 = iq*4;
      float w0=W2[(i0+0)*128+j], w1=W2[(i0+1)*128+j], w2=W2[(i0+2)*128+j], w3=W2[(i0+3)*128+j];
      #pragma unroll
      for (int h=0;h<8;h++){
        float4 xv = *reinterpret_cast<const float4*>(&H1[rh*8+h][i0]);
        acc2[h] += xv.x*w0 + xv.y*w1 + xv.z*w2 + xv.w*w3;
      }
    }
    float part[8];
    #pragma unroll
    for (int h=0;h<8;h++) part[h] = silu_f(acc2[h]) * w3j[h];
    #pragma unroll
    for (int off=32; off>=1; off>>=1){
      #pragma unroll
      for (int h=0;h<8;h++) part[h] += __shfl_xor(part[h], off, 64);
    }
    const int wv = t >> 6;
    if ((t & 63) == 0){
      #pragma unroll
      for (int h=0;h<8;h++) scsum[wv][h] = part[h];
    }
    __syncthreads();
    if (t < 16){
      int ps = t>>3, h = t&7;
      sc_l[sb*2+ps][h] = scsum[2*ps][h] + scsum[2*ps+1][h] + b3[h];
    }
    __syncthreads();
  }

  // ---- softmax over the 16 pairs, per head ----
  if (t < 8){
    const int h = t;
    float m = -1e30f;
    for (int p2=0;p2<16;p2++) m = fmaxf(m, sc_l[p2][h]);
    float den = 0.f;
    for (int p2=0;p2<16;p2++){ float w = __expf(sc_l[p2][h]-m); attn_l[p2][h]=w; den += w; }
    float inv = 1.f/den;
    for (int p2=0;p2<16;p2++) attn_l[p2][h] *= inv;
  }
  __syncthreads();

  // ---- aggregation ----
  if (t < 128){
    const int h = t>>4;
    float s = 0.f;
    #pragma unroll
    for (int p2=0;p2<16;p2++) s += attn_l[p2][h]*v_l[p2][t];
    feats[t] = s;
  }
  if (t >= 128 && t < 144){
    int p2 = t-128;
    float s = 0.f;
    #pragma unroll
    for (int h=0;h<8;h++) s += attn_l[p2][h]*gate_l[p2][h];
    cd_l[p2][3] = s;   // reuse: per-pair gate-weighted attention mass
  }
  __syncthreads();
  if (t < 3){
    float s = 0.f;
    #pragma unroll
    for (int p2=0;p2<16;p2++) s += cd_l[p2][3]*cd_l[p2][t];
    out_c[e*3+t] = coords[e*3+t] + s*0.125f;
  }

  // ---- y = ef + feats@Wo + bo, then layernorm ----
  float yv = 0.f;
  if (t < 128){
    float a = bo[t];
    for (int iq=0;iq<32;iq++){
      int i0 = iq*4;
      float4 f4 = *reinterpret_cast<const float4*>(&feats[i0]);
      a += f4.x*Wo[(i0+0)*128+t] + f4.y*Wo[(i0+1)*128+t]
         + f4.z*Wo[(i0+2)*128+t] + f4.w*Wo[(i0+3)*128+t];
    }
    yv = ef[e*128+t] + a;
    float s1 = yv, s2 = yv*yv;
    #pragma unroll
    for (int off=32; off>=1; off>>=1){ s1 += __shfl_xor(s1,off,64); s2 += __shfl_xor(s2,off,64); }
    if ((t&63)==0){ red[(t>>6)*2+0]=s1; red[(t>>6)*2+1]=s2; }
  }
  __syncthreads();
  if (t < 128){
    float sm = red[0]+red[2], sq = red[1]+red[3];
    float mean = sm * (1.f/128.f);
    float var  = sq * (1.f/128.f) - mean*mean;
    float rstd = rsqrtf(var + 1e-5f);
    out_y[e*128+t] = (yv-mean)*rstd*gamma[t] + beta[t];
  }
}

extern "C" void kernel_launch(void* const* d_in, const int* in_sizes, int n_in,
                              void* d_out, int out_size, void* d_ws, size_t ws_size,
                              hipStream_t stream)
{
  const float* ef     = (const float*)d_in[0];
  const float* coords = (const float*)d_in[1];
  const float* Wq  = (const float*)d_in[2];
  const float* Wk  = (const float*)d_in[3];
  const float* Wv  = (const float*)d_in[4];
  const float* W1  = (const float*)d_in[5];
  const float* b1  = (const float*)d_in[6];
  const float* W2  = (const float*)d_in[7];
  const float* b2  = (const float*)d_in[8];
  const float* W3  = (const float*)d_in[9];
  const float* b3  = (const float*)d_in[10];
  const float* Wg1 = (const float*)d_in[11];
  const float* bg1 = (const float*)d_in[12];
  const float* Wg2 = (const float*)d_in[13];
  const float* bg2 = (const float*)d_in[14];
  const float* Wo  = (const float*)d_in[15];
  const float* bo  = (const float*)d_in[16];
  const float* gamma = (const float*)d_in[17];
  const float* beta  = (const float*)d_in[18];
  const int*   pairs = (const int*)d_in[19];

  float* ws   = (float*)d_ws;
  float* q    = ws;
  float* k    = q + E_N*HID;
  float* v    = k + E_N*HID;
  float* gate = v + E_N*HID;

  qkv_kernel<<<E_N/16, 256, 0, stream>>>(ef, Wq, Wk, Wv, q, k, v);
  gate_kernel<<<E_N, 256, 0, stream>>>(v, Wg1, bg1, Wg2, bg2, gate);
  edge_attn_kernel<<<E_N, 256, 0, stream>>>(ef, coords, q, k, v,
      W1,b1,W2,b2,W3,b3,Wo,bo,gamma,beta,pairs,gate,
      (float*)d_out, (float*)d_out + E_N*HID);
}

// Round 2
// 312.519 us; speedup vs baseline: 4.3037x; 4.3037x over previous
//
#include <hip/hip_runtime.h>
#include <hip/hip_bf16.h>
#include <math.h>

#define E_N   8192
#define K_N   16
#define HID   128
#define HEADS 8
#define HD    16
#define NRAD  64

typedef unsigned short ushort_t;
typedef __attribute__((ext_vector_type(8))) short bf16x8;
typedef __attribute__((ext_vector_type(4))) float f32x4;

__device__ __forceinline__ float silu_f(float x){ return x / (1.f + __expf(-x)); }
__device__ __forceinline__ float sigmoid_f(float x){ return 1.f / (1.f + __expf(-x)); }

__device__ __forceinline__ ushort_t f2b(float x){
  union { __hip_bfloat16 b; ushort_t u; } cv;
  cv.b = __float2bfloat16(x);
  return cv.u;
}
__device__ __forceinline__ void st2(ushort_t* p, float a, float b){
  unsigned int v = (unsigned int)f2b(a) | ((unsigned int)f2b(b) << 16);
  *reinterpret_cast<unsigned int*>(p) = v;
}

// ---------------- Kernel A: q,k,v = ef @ {Wq,Wk,Wv} (fp32) ----------------
__global__ __launch_bounds__(256) void qkv_kernel(
    const float* __restrict__ ef,
    const float* __restrict__ Wq, const float* __restrict__ Wk, const float* __restrict__ Wv,
    float* __restrict__ q, float* __restrict__ k, float* __restrict__ v)
{
  __shared__ float efl[16][128];
  const int t = threadIdx.x;
  const int base = blockIdx.x * 16;
  for (int idx = t; idx < 16*128; idx += 256)
    efl[idx>>7][idx&127] = ef[base*128 + idx];
  __syncthreads();

  const int j = t & 127, half = t >> 7;
  float aq[8], ak[8], av[8];
  #pragma unroll
  for (int r=0;r<8;r++){ aq[r]=0.f; ak[r]=0.f; av[r]=0.f; }
  for (int i=0;i<128;i++){
    float wq = Wq[i*128+j], wk = Wk[i*128+j], wv = Wv[i*128+j];
    #pragma unroll
    for (int r=0;r<8;r++){
      float x = efl[half*8+r][i];
      aq[r] += x*wq; ak[r] += x*wk; av[r] += x*wv;
    }
  }
  #pragma unroll
  for (int r=0;r<8;r++){
    int row = base + half*8 + r;
    q[row*128+j]=aq[r]; k[row*128+j]=ak[r]; v[row*128+j]=av[r];
  }
}

// ---------------- Kernel B: gate[e][h] ----------------
__global__ __launch_bounds__(256) void gate_kernel(
    const float* __restrict__ v,
    const float* __restrict__ Wg1, const float* __restrict__ bg1,
    const float* __restrict__ Wg2, const float* __restrict__ bg2,
    float* __restrict__ gate)
{
  const int e = blockIdx.x;
  const int t = threadIdx.x;
  const int h = t >> 5, l = t & 31;
  float vp[16];
  #pragma unroll
  for (int i=0;i<16;i++) vp[i] = v[e*128 + h*16 + i];
  float part = 0.f;
  #pragma unroll
  for (int jj=0;jj<4;jj++){
    int j = l + jj*32;
    float a = bg1[j];
    #pragma unroll
    for (int i=0;i<16;i++) a += vp[i]*Wg1[i*128+j];
    part += silu_f(a) * Wg2[j];
  }
  #pragma unroll
  for (int off=16; off>=1; off>>=1) part += __shfl_xor(part, off, 64);
  if (l==0) gate[e*8+h] = sigmoid_f(part + bg2[0]);
}

// ---------------- Kernel W: pack W1/W2 into MFMA B-fragment-linear bf16 ----------------
// W1f[ks][nf][lane][i] = W1[k][n], k = ks*32+(lane>>4)*8+i (0 if k>=97), n = nf*16+(lane&15)
// W2f same with W2 (k always < 128).
__global__ __launch_bounds__(256) void wprep_kernel(
    const float* __restrict__ W1, const float* __restrict__ W2,
    ushort_t* __restrict__ W1f, ushort_t* __restrict__ W2f)
{
  int idx = blockIdx.x*256 + threadIdx.x;    // 0..32767
  int id  = idx & 16383;
  int i  = id & 7;
  int l  = (id >> 3) & 63;
  int nf = (id >> 9) & 7;
  int ks = (id >> 12) & 3;
  int kk = ks*32 + (l>>4)*8 + i;
  int n  = nf*16 + (l&15);
  if (idx < 16384){
    float val = (kk < 97) ? W1[kk*128 + n] : 0.f;
    W1f[id] = f2b(val);
  } else {
    W2f[id] = f2b(W2[kk*128 + n]);
  }
}

// ---------------- Kernel C: MFMA fused edge attention ----------------
__global__ __launch_bounds__(256) void edge_attn_mfma(
    const float* __restrict__ ef, const float* __restrict__ coords,
    const float* __restrict__ q, const float* __restrict__ k, const float* __restrict__ v,
    const ushort_t* __restrict__ W1f, const ushort_t* __restrict__ W2f,
    const float* __restrict__ b1, const float* __restrict__ b2,
    const float* __restrict__ W3, const float* __restrict__ b3,
    const float* __restrict__ Wo, const float* __restrict__ bo,
    const float* __restrict__ gamma, const float* __restrict__ beta,
    const int* __restrict__ pairs, const float* __restrict__ gate,
    float* __restrict__ out_y, float* __restrict__ out_c)
{
  // X: [128 rows][stride 120] bf16, rows = p*8+h, cols: 0..15 q, 16..31 k, 32..95 rb,
  //    96 dot, 97..119 zero. +8 u16 zero tail (layer-1 ks=3 over-read safety).
  __shared__ __align__(16) ushort_t Xs[15368];       // 30736 B (later aliased: scpart[4][128] f32)
  __shared__ __align__(16) ushort_t H1s[16384];      // 32768 B, [128][128] XOR-swizzled
                                                     // (early alias: rbtmp[16][64] f32;
                                                     //  late alias: sc/attn/feats/red)
  __shared__ float cd_l[16][4];
  __shared__ float gate_l[16][8];
  __shared__ int   dstl[16];

  float* rbtmp  = (float*)H1s;            // [16][64] during X build
  float* scpart = (float*)Xs;             // [4][128] after layer2
  float* sc_l   = (float*)H1s;            // [128] rows p*8+h
  float* attn_l = sc_l + 128;             // [128]
  float* feats  = attn_l + 128;           // [128]
  float* red    = feats + 128;            // [4]

  const int e = blockIdx.x;
  const int t = threadIdx.x;

  if (t < 16) dstl[t] = pairs[(e*16 + t)*2 + 1];
  __syncthreads();

  if (t < 16){
    int d = dstl[t];
    float cx = coords[e*3+0]-coords[d*3+0];
    float cy = coords[e*3+1]-coords[d*3+1];
    float cz = coords[e*3+2]-coords[d*3+2];
    cd_l[t][0]=cx; cd_l[t][1]=cy; cd_l[t][2]=cz;
    cd_l[t][3]=sqrtf(cx*cx+cy*cy+cz*cz);
  }
  if (t >= 128){
    int idx = t - 128; int p = idx>>3, h = idx&7;
    gate_l[p][h] = gate[dstl[p]*8 + h];
  }
  __syncthreads();

  // rb (fp32 temp in H1s region)
  for (int idx = t; idx < 16*64; idx += 256){
    int p = idx >> 6, i = idx & 63;
    float c = (float)i * (10.0f/63.0f);
    float z = (cd_l[p][3] - c) * (64.0f/10.0f);
    rbtmp[idx] = __expf(-z*z);
  }
  __syncthreads();

  // ---- build X (bf16) ----
  {
    const int r = t >> 1, seg = t & 1;
    const int p = r >> 3, h = r & 7;
    ushort_t* Xrow = Xs + r*120;
    if (seg == 0){
      const float* qp = q + e*128 + h*16;
      const float* kp = k + dstl[p]*128 + h*16;
      float dot = 0.f;
      #pragma unroll
      for (int i=0;i<16;i+=2){
        float q0=qp[i], q1=qp[i+1], k0=kp[i], k1=kp[i+1];
        dot += q0*k0 + q1*k1;
        st2(Xrow + i,      q0, q1);
        st2(Xrow + 16 + i, k0, k1);
      }
      Xrow[96] = f2b(dot);
      #pragma unroll
      for (int c=97;c<120;c++) Xrow[c] = 0;
    } else {
      const float* rbp = rbtmp + p*64;
      #pragma unroll
      for (int i=0;i<64;i+=2)
        st2(Xrow + 32 + i, rbp[i], rbp[i+1]);
    }
    if (t < 8) Xs[15360+t] = 0;
  }
  __syncthreads();

  const int wv = t >> 6;        // wave id: owns N cols [wv*32, wv*32+32)
  const int l  = t & 63;
  const int lr = l & 15;        // row-in-frag (A) / col (B,C)
  const int lg = l >> 4;        // k-group / row-group

  // ---- layer 1: C1[128][128] = X[128][128] @ W1 ----
  bf16x8 B1[4][2];
  #pragma unroll
  for (int ks=0; ks<4; ks++)
    #pragma unroll
    for (int nf=0; nf<2; nf++)
      B1[ks][nf] = *reinterpret_cast<const bf16x8*>(W1f + ((ks*8 + wv*2+nf)*64 + l)*8);

  f32x4 acc[8][2];
  #pragma unroll
  for (int mf=0;mf<8;mf++){ acc[mf][0] = (f32x4)0.f; acc[mf][1] = (f32x4)0.f; }

  for (int mf=0; mf<8; mf++){
    const ushort_t* arow = Xs + (mf*16 + lr)*120 + lg*8;
    bf16x8 A0 = *reinterpret_cast<const bf16x8*>(arow);
    bf16x8 A1 = *reinterpret_cast<const bf16x8*>(arow + 32);
    bf16x8 A2 = *reinterpret_cast<const bf16x8*>(arow + 64);
    bf16x8 A3 = *reinterpret_cast<const bf16x8*>(arow + 96);
    acc[mf][0] = __builtin_amdgcn_mfma_f32_16x16x32_bf16(A0, B1[0][0], acc[mf][0], 0,0,0);
    acc[mf][1] = __builtin_amdgcn_mfma_f32_16x16x32_bf16(A0, B1[0][1], acc[mf][1], 0,0,0);
    acc[mf][0] = __builtin_amdgcn_mfma_f32_16x16x32_bf16(A1, B1[1][0], acc[mf][0], 0,0,0);
    acc[mf][1] = __builtin_amdgcn_mfma_f32_16x16x32_bf16(A1, B1[1][1], acc[mf][1], 0,0,0);
    acc[mf][0] = __builtin_amdgcn_mfma_f32_16x16x32_bf16(A2, B1[2][0], acc[mf][0], 0,0,0);
    acc[mf][1] = __builtin_amdgcn_mfma_f32_16x16x32_bf16(A2, B1[2][1], acc[mf][1], 0,0,0);
    acc[mf][0] = __builtin_amdgcn_mfma_f32_16x16x32_bf16(A3, B1[3][0], acc[mf][0], 0,0,0);
    acc[mf][1] = __builtin_amdgcn_mfma_f32_16x16x32_bf16(A3, B1[3][1], acc[mf][1], 0,0,0);
  }

  // silu + bf16 -> H1 (XOR-swizzled [128][128])
  {
    float b1v0 = b1[wv*32 + lr];
    float b1v1 = b1[wv*32 + 16 + lr];
    #pragma unroll
    for (int mf=0;mf<8;mf++){
      #pragma unroll
      for (int i=0;i<4;i++){
        int row = mf*16 + lg*4 + i;
        unsigned int swz = (unsigned int)((row & 7) << 4);
        {
          int col = wv*32 + lr;
          unsigned int byte = (unsigned int)(row*256 + col*2) ^ swz;
          *reinterpret_cast<ushort_t*>(reinterpret_cast<char*>(H1s) + byte) = f2b(silu_f(acc[mf][0][i] + b1v0));
        }
        {
          int col = wv*32 + 16 + lr;
          unsigned int byte = (unsigned int)(row*256 + col*2) ^ swz;
          *reinterpret_cast<ushort_t*>(reinterpret_cast<char*>(H1s) + byte) = f2b(silu_f(acc[mf][1][i] + b1v1));
        }
      }
    }
  }
  __syncthreads();

  // ---- layer 2: C2[128][128] = H1 @ W2 ----
  bf16x8 B2[4][2];
  #pragma unroll
  for (int ks=0; ks<4; ks++)
    #pragma unroll
    for (int nf=0; nf<2; nf++)
      B2[ks][nf] = *reinterpret_cast<const bf16x8*>(W2f + ((ks*8 + wv*2+nf)*64 + l)*8);

  #pragma unroll
  for (int mf=0;mf<8;mf++){ acc[mf][0] = (f32x4)0.f; acc[mf][1] = (f32x4)0.f; }

  for (int mf=0; mf<8; mf++){
    int row = mf*16 + lr;
    unsigned int swz = (unsigned int)((row & 7) << 4);
    #pragma unroll
    for (int ks=0; ks<4; ks++){
      unsigned int byte = (unsigned int)(row*256 + (ks*32 + lg*8)*2) ^ swz;
      bf16x8 A = *reinterpret_cast<const bf16x8*>(reinterpret_cast<const char*>(H1s) + byte);
      acc[mf][0] = __builtin_amdgcn_mfma_f32_16x16x32_bf16(A, B2[ks][0], acc[mf][0], 0,0,0);
      acc[mf][1] = __builtin_amdgcn_mfma_f32_16x16x32_bf16(A, B2[ks][1], acc[mf][1], 0,0,0);
    }
  }

  // ---- scores: silu(C2+b2) dot W3 column h(row), reduced in-register ----
  {
    float b2v0 = b2[wv*32 + lr];
    float b2v1 = b2[wv*32 + 16 + lr];
    float w3v0[4], w3v1[4];
    #pragma unroll
    for (int i=0;i<4;i++){
      int h = (lg*4 + i) & 7;
      w3v0[i] = W3[(wv*32 + lr)*8 + h];
      w3v1[i] = W3[(wv*32 + 16 + lr)*8 + h];
    }
    float prt[8][4];
    #pragma unroll
    for (int mf=0;mf<8;mf++)
      #pragma unroll
      for (int i=0;i<4;i++)
        prt[mf][i] = silu_f(acc[mf][0][i] + b2v0) * w3v0[i]
                   + silu_f(acc[mf][1][i] + b2v1) * w3v1[i];
    #pragma unroll
    for (int off=1; off<16; off<<=1)
      #pragma unroll
      for (int mf=0;mf<8;mf++)
        #pragma unroll
        for (int i=0;i<4;i++)
          prt[mf][i] += __shfl_xor(prt[mf][i], off, 64);
    if (lr == 0){
      #pragma unroll
      for (int mf=0;mf<8;mf++)
        #pragma unroll
        for (int i=0;i<4;i++)
          scpart[wv*128 + mf*16 + lg*4 + i] = prt[mf][i];
    }
  }
  __syncthreads();

  // finalize scores (rows p*8+h)
  if (t < 128){
    float s = scpart[t] + scpart[128+t] + scpart[256+t] + scpart[384+t] + b3[t&7];
    sc_l[t] = s;
  }
  __syncthreads();

  // softmax over 16 pairs per head
  if (t < 8){
    const int h = t;
    float m = -1e30f;
    for (int p=0;p<16;p++) m = fmaxf(m, sc_l[p*8+h]);
    float den = 0.f;
    for (int p=0;p<16;p++){ float w = __expf(sc_l[p*8+h]-m); attn_l[p*8+h]=w; den += w; }
    float inv = 1.f/den;
    for (int p=0;p<16;p++) attn_l[p*8+h] *= inv;
  }
  __syncthreads();

  // aggregation
  if (t < 128){
    const int h = t >> 4;
    float s = 0.f;
    #pragma unroll
    for (int p=0;p<16;p++) s += attn_l[p*8+h] * v[dstl[p]*128 + t];
    feats[t] = s;
  }
  if (t >= 128 && t < 144){
    int p = t-128;
    float s = 0.f;
    #pragma unroll
    for (int h=0;h<8;h++) s += attn_l[p*8+h]*gate_l[p][h];
    cd_l[p][3] = s;
  }
  __syncthreads();
  if (t < 3){
    float s = 0.f;
    #pragma unroll
    for (int p=0;p<16;p++) s += cd_l[p][3]*cd_l[p][t];
    out_c[e*3+t] = coords[e*3+t] + s*0.125f;
  }

  // y = ef + feats@Wo + bo, layernorm
  float yv = 0.f;
  if (t < 128){
    float a = bo[t];
    for (int iq=0;iq<32;iq++){
      int i0 = iq*4;
      float4 f4 = *reinterpret_cast<const float4*>(&feats[i0]);
      a += f4.x*Wo[(i0+0)*128+t] + f4.y*Wo[(i0+1)*128+t]
         + f4.z*Wo[(i0+2)*128+t] + f4.w*Wo[(i0+3)*128+t];
    }
    yv = ef[e*128+t] + a;
    float s1 = yv, s2 = yv*yv;
    #pragma unroll
    for (int off=32; off>=1; off>>=1){ s1 += __shfl_xor(s1,off,64); s2 += __shfl_xor(s2,off,64); }
    if ((t&63)==0){ red[(t>>6)*2+0]=s1; red[(t>>6)*2+1]=s2; }
  }
  __syncthreads();
  if (t < 128){
    float sm = red[0]+red[2], sq = red[1]+red[3];
    float mean = sm * (1.f/128.f);
    float var  = sq * (1.f/128.f) - mean*mean;
    float rstd = rsqrtf(var + 1e-5f);
    out_y[e*128+t] = (yv-mean)*rstd*gamma[t] + beta[t];
  }
}

extern "C" void kernel_launch(void* const* d_in, const int* in_sizes, int n_in,
                              void* d_out, int out_size, void* d_ws, size_t ws_size,
                              hipStream_t stream)
{
  const float* ef     = (const float*)d_in[0];
  const float* coords = (const float*)d_in[1];
  const float* Wq  = (const float*)d_in[2];
  const float* Wk  = (const float*)d_in[3];
  const float* Wv  = (const float*)d_in[4];
  const float* W1  = (const float*)d_in[5];
  const float* b1  = (const float*)d_in[6];
  const float* W2  = (const float*)d_in[7];
  const float* b2  = (const float*)d_in[8];
  const float* W3  = (const float*)d_in[9];
  const float* b3  = (const float*)d_in[10];
  const float* Wg1 = (const float*)d_in[11];
  const float* bg1 = (const float*)d_in[12];
  const float* Wg2 = (const float*)d_in[13];
  const float* bg2 = (const float*)d_in[14];
  const float* Wo  = (const float*)d_in[15];
  const float* bo  = (const float*)d_in[16];
  const float* gamma = (const float*)d_in[17];
  const float* beta  = (const float*)d_in[18];
  const int*   pairs = (const int*)d_in[19];

  float* ws   = (float*)d_ws;
  float* q    = ws;
  float* k    = q + E_N*HID;
  float* v    = k + E_N*HID;
  float* gate = v + E_N*HID;
  ushort_t* W1f = (ushort_t*)(gate + E_N*HEADS);
  ushort_t* W2f = W1f + 16384;

  qkv_kernel<<<E_N/16, 256, 0, stream>>>(ef, Wq, Wk, Wv, q, k, v);
  wprep_kernel<<<128, 256, 0, stream>>>(W1, W2, W1f, W2f);
  gate_kernel<<<E_N, 256, 0, stream>>>(v, Wg1, bg1, Wg2, bg2, gate);
  edge_attn_mfma<<<E_N, 256, 0, stream>>>(ef, coords, q, k, v,
      W1f, W2f, b1, b2, W3, b3, Wo, bo, gamma, beta, pairs, gate,
      (float*)d_out, (float*)d_out + E_N*HID);
}

// Round 3
// 278.397 us; speedup vs baseline: 4.8312x; 1.1226x over previous
//
#include <hip/hip_runtime.h>
#include <hip/hip_bf16.h>
#include <math.h>

#define E_N   8192
#define K_N   16
#define HID   128
#define HEADS 8
#define HD    16
#define NRAD  64

typedef unsigned short ushort_t;
typedef __attribute__((ext_vector_type(8))) short bf16x8;
typedef __attribute__((ext_vector_type(4))) float f32x4;

__device__ __forceinline__ float fast_rcp(float x){ return __builtin_amdgcn_rcpf(x); }
__device__ __forceinline__ float silu_f(float x){ return x * fast_rcp(1.f + __expf(-x)); }
__device__ __forceinline__ float sigmoid_f(float x){ return fast_rcp(1.f + __expf(-x)); }

__device__ __forceinline__ ushort_t f2b(float x){
  union { __hip_bfloat16 b; ushort_t u; } cv;
  cv.b = __float2bfloat16(x);
  return cv.u;
}
__device__ __forceinline__ void st2(ushort_t* p, float a, float b){
  unsigned int v = (unsigned int)f2b(a) | ((unsigned int)f2b(b) << 16);
  *reinterpret_cast<unsigned int*>(p) = v;
}

// ---------------- Kernel A: q,k,v = ef @ {Wq,Wk,Wv} (fp32) ----------------
__global__ __launch_bounds__(256) void qkv_kernel(
    const float* __restrict__ ef,
    const float* __restrict__ Wq, const float* __restrict__ Wk, const float* __restrict__ Wv,
    float* __restrict__ q, float* __restrict__ k, float* __restrict__ v)
{
  __shared__ float efl[16][128];
  const int t = threadIdx.x;
  const int base = blockIdx.x * 16;
  for (int idx = t; idx < 16*128; idx += 256)
    efl[idx>>7][idx&127] = ef[base*128 + idx];
  __syncthreads();

  const int j = t & 127, half = t >> 7;
  float aq[8], ak[8], av[8];
  #pragma unroll
  for (int r=0;r<8;r++){ aq[r]=0.f; ak[r]=0.f; av[r]=0.f; }
  for (int i=0;i<128;i++){
    float wq = Wq[i*128+j], wk = Wk[i*128+j], wv = Wv[i*128+j];
    #pragma unroll
    for (int r=0;r<8;r++){
      float x = efl[half*8+r][i];
      aq[r] += x*wq; ak[r] += x*wk; av[r] += x*wv;
    }
  }
  #pragma unroll
  for (int r=0;r<8;r++){
    int row = base + half*8 + r;
    q[row*128+j]=aq[r]; k[row*128+j]=ak[r]; v[row*128+j]=av[r];
  }
}

// ---------------- Kernel B: gate[e][h] ----------------
__global__ __launch_bounds__(256) void gate_kernel(
    const float* __restrict__ v,
    const float* __restrict__ Wg1, const float* __restrict__ bg1,
    const float* __restrict__ Wg2, const float* __restrict__ bg2,
    float* __restrict__ gate)
{
  const int e = blockIdx.x;
  const int t = threadIdx.x;
  const int h = t >> 5, l = t & 31;
  float vp[16];
  #pragma unroll
  for (int i=0;i<16;i++) vp[i] = v[e*128 + h*16 + i];
  float part = 0.f;
  #pragma unroll
  for (int jj=0;jj<4;jj++){
    int j = l + jj*32;
    float a = bg1[j];
    #pragma unroll
    for (int i=0;i<16;i++) a += vp[i]*Wg1[i*128+j];
    part += silu_f(a) * Wg2[j];
  }
  #pragma unroll
  for (int off=16; off>=1; off>>=1) part += __shfl_xor(part, off, 64);
  if (l==0) gate[e*8+h] = sigmoid_f(part + bg2[0]);
}

// ---------------- Kernel W: pack W1/W2/W3 into MFMA B-fragment-linear bf16 --------
// B-frag layout for 16x16x32: frag[ks][nf][lane][i], k = ks*32+(lane>>4)*8+i,
// n = nf*16+(lane&15). W1 zero-padded K 97->128; W3 zero-padded N 8->16.
__global__ __launch_bounds__(256) void wprep_kernel(
    const float* __restrict__ W1, const float* __restrict__ W2, const float* __restrict__ W3,
    ushort_t* __restrict__ W1f, ushort_t* __restrict__ W2f, ushort_t* __restrict__ W3f)
{
  int idx = blockIdx.x*256 + threadIdx.x;    // 0..34815
  if (idx < 32768){
    int id  = idx & 16383;
    int i  = id & 7;
    int l  = (id >> 3) & 63;
    int nf = (id >> 9) & 7;
    int ks = (id >> 12) & 3;
    int kk = ks*32 + (l>>4)*8 + i;
    int n  = nf*16 + (l&15);
    if (idx < 16384){
      float val = (kk < 97) ? W1[kk*128 + n] : 0.f;
      W1f[id] = f2b(val);
    } else {
      W2f[id] = f2b(W2[kk*128 + n]);
    }
  } else {
    int id = idx - 32768;                    // 0..2047
    int i  = id & 7;
    int l  = (id >> 3) & 63;
    int ks = (id >> 9) & 3;
    int kk = ks*32 + (l>>4)*8 + i;
    int n  = l & 15;
    W3f[id] = (n < 8) ? f2b(W3[kk*8 + n]) : (ushort_t)0;
  }
}

// ---------------- Kernel C: MFMA fused edge attention ----------------
__global__ __launch_bounds__(256, 4) void edge_attn_mfma(
    const float* __restrict__ ef, const float* __restrict__ coords,
    const float* __restrict__ q, const float* __restrict__ k, const float* __restrict__ v,
    const ushort_t* __restrict__ W1f, const ushort_t* __restrict__ W2f,
    const ushort_t* __restrict__ W3f,
    const float* __restrict__ b1, const float* __restrict__ b2,
    const float* __restrict__ b3,
    const float* __restrict__ Wo, const float* __restrict__ bo,
    const float* __restrict__ gamma, const float* __restrict__ beta,
    const int* __restrict__ pairs, const float* __restrict__ gate,
    float* __restrict__ out_y, float* __restrict__ out_c)
{
  // BufA (32 KB) time-shares three tenants:
  //   phase 1: X [128 rows][stride 120 u16] + 8 u16 zero tail
  //   phase 2: H1 [128][128] bf16, XOR-swizzled (byte ^= (row&7)<<4)
  //   phase 3: H2, same layout as H1
  __shared__ __align__(16) ushort_t BufA[16384];
  // SmallBuf (4 KB) time-shares: rbtmp[16][64] f32  ->  sc[128]/attn[128]/feats[128]/red[4]
  __shared__ __align__(16) float SmallBuf[1024];
  __shared__ float cd_l[16][4];
  __shared__ float gate_l[16][8];
  __shared__ int   dstl[16];

  float* rbtmp  = SmallBuf;
  float* sc_l   = SmallBuf;
  float* attn_l = SmallBuf + 128;
  float* feats  = SmallBuf + 256;
  float* red    = SmallBuf + 384;

  const int e = blockIdx.x;
  const int t = threadIdx.x;

  if (t < 16) dstl[t] = pairs[(e*16 + t)*2 + 1];
  __syncthreads();

  if (t < 16){
    int d = dstl[t];
    float cx = coords[e*3+0]-coords[d*3+0];
    float cy = coords[e*3+1]-coords[d*3+1];
    float cz = coords[e*3+2]-coords[d*3+2];
    cd_l[t][0]=cx; cd_l[t][1]=cy; cd_l[t][2]=cz;
    cd_l[t][3]=sqrtf(cx*cx+cy*cy+cz*cz);
  }
  if (t >= 128){
    int idx = t - 128; int p = idx>>3, h = idx&7;
    gate_l[p][h] = gate[dstl[p]*8 + h];
  }
  __syncthreads();

  // rb (fp32 temp)
  for (int idx = t; idx < 16*64; idx += 256){
    int p = idx >> 6, i = idx & 63;
    float c = (float)i * (10.0f/63.0f);
    float z = (cd_l[p][3] - c) * (64.0f/10.0f);
    rbtmp[idx] = __expf(-z*z);
  }
  __syncthreads();

  // ---- build X (bf16) ----
  {
    const int r = t >> 1, seg = t & 1;
    const int p = r >> 3, h = r & 7;
    ushort_t* Xrow = BufA + r*120;
    if (seg == 0){
      const float4* qp4 = reinterpret_cast<const float4*>(q + e*128 + h*16);
      const float4* kp4 = reinterpret_cast<const float4*>(k + dstl[p]*128 + h*16);
      float dot = 0.f;
      #pragma unroll
      for (int i4=0;i4<4;i4++){
        float4 qv = qp4[i4], kv = kp4[i4];
        dot += qv.x*kv.x + qv.y*kv.y + qv.z*kv.z + qv.w*kv.w;
        st2(Xrow + i4*4,      qv.x, qv.y); st2(Xrow + i4*4+2,      qv.z, qv.w);
        st2(Xrow + 16+i4*4,   kv.x, kv.y); st2(Xrow + 16+i4*4+2,   kv.z, kv.w);
      }
      Xrow[96] = f2b(dot);
      #pragma unroll
      for (int c=97;c<120;c++) Xrow[c] = 0;
    } else {
      const float4* rbp = reinterpret_cast<const float4*>(rbtmp + p*64);
      #pragma unroll
      for (int i4=0;i4<16;i4++){
        float4 rv = rbp[i4];
        st2(Xrow + 32 + i4*4,   rv.x, rv.y);
        st2(Xrow + 32 + i4*4+2, rv.z, rv.w);
      }
    }
    if (t < 8) BufA[15360+t] = 0;
  }
  __syncthreads();

  const int wv = t >> 6;        // wave id: owns N cols [wv*32, wv*32+32)
  const int l  = t & 63;
  const int lr = l & 15;
  const int lg = l >> 4;

  f32x4 acc[8][2];

  // ---- layer 1: C1 = X @ W1 ----
  {
    bf16x8 B1[4][2];
    #pragma unroll
    for (int ks=0; ks<4; ks++)
      #pragma unroll
      for (int nf=0; nf<2; nf++)
        B1[ks][nf] = *reinterpret_cast<const bf16x8*>(W1f + ((ks*8 + wv*2+nf)*64 + l)*8);

    #pragma unroll
    for (int mf=0;mf<8;mf++){ acc[mf][0] = (f32x4)0.f; acc[mf][1] = (f32x4)0.f; }

    for (int mf=0; mf<8; mf++){
      const ushort_t* arow = BufA + (mf*16 + lr)*120 + lg*8;
      bf16x8 A0 = *reinterpret_cast<const bf16x8*>(arow);
      bf16x8 A1 = *reinterpret_cast<const bf16x8*>(arow + 32);
      bf16x8 A2 = *reinterpret_cast<const bf16x8*>(arow + 64);
      bf16x8 A3 = *reinterpret_cast<const bf16x8*>(arow + 96);
      acc[mf][0] = __builtin_amdgcn_mfma_f32_16x16x32_bf16(A0, B1[0][0], acc[mf][0], 0,0,0);
      acc[mf][1] = __builtin_amdgcn_mfma_f32_16x16x32_bf16(A0, B1[0][1], acc[mf][1], 0,0,0);
      acc[mf][0] = __builtin_amdgcn_mfma_f32_16x16x32_bf16(A1, B1[1][0], acc[mf][0], 0,0,0);
      acc[mf][1] = __builtin_amdgcn_mfma_f32_16x16x32_bf16(A1, B1[1][1], acc[mf][1], 0,0,0);
      acc[mf][0] = __builtin_amdgcn_mfma_f32_16x16x32_bf16(A2, B1[2][0], acc[mf][0], 0,0,0);
      acc[mf][1] = __builtin_amdgcn_mfma_f32_16x16x32_bf16(A2, B1[2][1], acc[mf][1], 0,0,0);
      acc[mf][0] = __builtin_amdgcn_mfma_f32_16x16x32_bf16(A3, B1[3][0], acc[mf][0], 0,0,0);
      acc[mf][1] = __builtin_amdgcn_mfma_f32_16x16x32_bf16(A3, B1[3][1], acc[mf][1], 0,0,0);
    }
  }
  __syncthreads();   // all X reads done; BufA can be overwritten

  // silu + bf16 -> H1 (swizzled), overwrites X
  {
    float b1v0 = b1[wv*32 + lr];
    float b1v1 = b1[wv*32 + 16 + lr];
    #pragma unroll
    for (int mf=0;mf<8;mf++){
      #pragma unroll
      for (int i=0;i<4;i++){
        int row = mf*16 + lg*4 + i;
        unsigned int swz = (unsigned int)((row & 7) << 4);
        {
          int col = wv*32 + lr;
          unsigned int byte = (unsigned int)(row*256 + col*2) ^ swz;
          *reinterpret_cast<ushort_t*>(reinterpret_cast<char*>(BufA) + byte) = f2b(silu_f(acc[mf][0][i] + b1v0));
        }
        {
          int col = wv*32 + 16 + lr;
          unsigned int byte = (unsigned int)(row*256 + col*2) ^ swz;
          *reinterpret_cast<ushort_t*>(reinterpret_cast<char*>(BufA) + byte) = f2b(silu_f(acc[mf][1][i] + b1v1));
        }
      }
    }
  }
  __syncthreads();

  // ---- layer 2: C2 = H1 @ W2 ----
  {
    bf16x8 B2[4][2];
    #pragma unroll
    for (int ks=0; ks<4; ks++)
      #pragma unroll
      for (int nf=0; nf<2; nf++)
        B2[ks][nf] = *reinterpret_cast<const bf16x8*>(W2f + ((ks*8 + wv*2+nf)*64 + l)*8);

    #pragma unroll
    for (int mf=0;mf<8;mf++){ acc[mf][0] = (f32x4)0.f; acc[mf][1] = (f32x4)0.f; }

    for (int mf=0; mf<8; mf++){
      int row = mf*16 + lr;
      unsigned int swz = (unsigned int)((row & 7) << 4);
      #pragma unroll
      for (int ks=0; ks<4; ks++){
        unsigned int byte = (unsigned int)(row*256 + (ks*32 + lg*8)*2) ^ swz;
        bf16x8 A = *reinterpret_cast<const bf16x8*>(reinterpret_cast<const char*>(BufA) + byte);
        acc[mf][0] = __builtin_amdgcn_mfma_f32_16x16x32_bf16(A, B2[ks][0], acc[mf][0], 0,0,0);
        acc[mf][1] = __builtin_amdgcn_mfma_f32_16x16x32_bf16(A, B2[ks][1], acc[mf][1], 0,0,0);
      }
    }
  }
  __syncthreads();   // all H1 reads done

  // silu + bf16 -> H2 (same swizzled layout), overwrites H1
  {
    float b2v0 = b2[wv*32 + lr];
    float b2v1 = b2[wv*32 + 16 + lr];
    #pragma unroll
    for (int mf=0;mf<8;mf++){
      #pragma unroll
      for (int i=0;i<4;i++){
        int row = mf*16 + lg*4 + i;
        unsigned int swz = (unsigned int)((row & 7) << 4);
        {
          int col = wv*32 + lr;
          unsigned int byte = (unsigned int)(row*256 + col*2) ^ swz;
          *reinterpret_cast<ushort_t*>(reinterpret_cast<char*>(BufA) + byte) = f2b(silu_f(acc[mf][0][i] + b2v0));
        }
        {
          int col = wv*32 + 16 + lr;
          unsigned int byte = (unsigned int)(row*256 + col*2) ^ swz;
          *reinterpret_cast<ushort_t*>(reinterpret_cast<char*>(BufA) + byte) = f2b(silu_f(acc[mf][1][i] + b2v1));
        }
      }
    }
  }
  __syncthreads();

  // ---- scores = H2 @ W3 (N padded to 16), each wave owns 2 M-fragments ----
  {
    bf16x8 B3[4];
    #pragma unroll
    for (int ks=0; ks<4; ks++)
      B3[ks] = *reinterpret_cast<const bf16x8*>(W3f + ((ks*64) + l)*8);

    #pragma unroll
    for (int m2=0; m2<2; m2++){
      int mf = wv*2 + m2;
      f32x4 accS = (f32x4)0.f;
      int row = mf*16 + lr;
      unsigned int swz = (unsigned int)((row & 7) << 4);
      #pragma unroll
      for (int ks=0; ks<4; ks++){
        unsigned int byte = (unsigned int)(row*256 + (ks*32 + lg*8)*2) ^ swz;
        bf16x8 A = *reinterpret_cast<const bf16x8*>(reinterpret_cast<const char*>(BufA) + byte);
        accS = __builtin_amdgcn_mfma_f32_16x16x32_bf16(A, B3[ks], accS, 0,0,0);
      }
      #pragma unroll
      for (int i=0;i<4;i++){
        int rin = lg*4 + i;              // row within 16-row fragment
        if (lr == (rin & 7))
          sc_l[mf*16 + rin] = accS[i] + b3[rin & 7];
      }
    }
  }
  __syncthreads();

  // softmax over 16 pairs per head (rows are p*8+h)
  if (t < 8){
    const int h = t;
    float m = -1e30f;
    for (int p=0;p<16;p++) m = fmaxf(m, sc_l[p*8+h]);
    float den = 0.f;
    for (int p=0;p<16;p++){ float w = __expf(sc_l[p*8+h]-m); attn_l[p*8+h]=w; den += w; }
    float inv = fast_rcp(den);
    for (int p=0;p<16;p++) attn_l[p*8+h] *= inv;
  }
  __syncthreads();

  // aggregation
  if (t < 128){
    const int h = t >> 4;
    float s = 0.f;
    #pragma unroll
    for (int p=0;p<16;p++) s += attn_l[p*8+h] * v[dstl[p]*128 + t];
    feats[t] = s;
  }
  if (t >= 128 && t < 144){
    int p = t-128;
    float s = 0.f;
    #pragma unroll
    for (int h=0;h<8;h++) s += attn_l[p*8+h]*gate_l[p][h];
    cd_l[p][3] = s;
  }
  __syncthreads();
  if (t < 3){
    float s = 0.f;
    #pragma unroll
    for (int p=0;p<16;p++) s += cd_l[p][3]*cd_l[p][t];
    out_c[e*3+t] = coords[e*3+t] + s*0.125f;
  }

  // y = ef + feats@Wo + bo, layernorm
  float yv = 0.f;
  if (t < 128){
    float a = bo[t];
    for (int iq=0;iq<32;iq++){
      int i0 = iq*4;
      float4 f4 = *reinterpret_cast<const float4*>(&feats[i0]);
      a += f4.x*Wo[(i0+0)*128+t] + f4.y*Wo[(i0+1)*128+t]
         + f4.z*Wo[(i0+2)*128+t] + f4.w*Wo[(i0+3)*128+t];
    }
    yv = ef[e*128+t] + a;
    float s1 = yv, s2 = yv*yv;
    #pragma unroll
    for (int off=32; off>=1; off>>=1){ s1 += __shfl_xor(s1,off,64); s2 += __shfl_xor(s2,off,64); }
    if ((t&63)==0){ red[(t>>6)*2+0]=s1; red[(t>>6)*2+1]=s2; }
  }
  __syncthreads();
  if (t < 128){
    float sm = red[0]+red[2], sq = red[1]+red[3];
    float mean = sm * (1.f/128.f);
    float var  = sq * (1.f/128.f) - mean*mean;
    float rstd = rsqrtf(var + 1e-5f);
    out_y[e*128+t] = (yv-mean)*rstd*gamma[t] + beta[t];
  }
}

extern "C" void kernel_launch(void* const* d_in, const int* in_sizes, int n_in,
                              void* d_out, int out_size, void* d_ws, size_t ws_size,
                              hipStream_t stream)
{
  const float* ef     = (const float*)d_in[0];
  const float* coords = (const float*)d_in[1];
  const float* Wq  = (const float*)d_in[2];
  const float* Wk  = (const float*)d_in[3];
  const float* Wv  = (const float*)d_in[4];
  const float* W1  = (const float*)d_in[5];
  const float* b1  = (const float*)d_in[6];
  const float* W2  = (const float*)d_in[7];
  const float* b2  = (const float*)d_in[8];
  const float* W3  = (const float*)d_in[9];
  const float* b3  = (const float*)d_in[10];
  const float* Wg1 = (const float*)d_in[11];
  const float* bg1 = (const float*)d_in[12];
  const float* Wg2 = (const float*)d_in[13];
  const float* bg2 = (const float*)d_in[14];
  const float* Wo  = (const float*)d_in[15];
  const float* bo  = (const float*)d_in[16];
  const float* gamma = (const float*)d_in[17];
  const float* beta  = (const float*)d_in[18];
  const int*   pairs = (const int*)d_in[19];

  float* ws   = (float*)d_ws;
  float* q    = ws;
  float* k    = q + E_N*HID;
  float* v    = k + E_N*HID;
  float* gate = v + E_N*HID;
  ushort_t* W1f = (ushort_t*)(gate + E_N*HEADS);
  ushort_t* W2f = W1f + 16384;
  ushort_t* W3f = W2f + 16384;

  qkv_kernel<<<E_N/16, 256, 0, stream>>>(ef, Wq, Wk, Wv, q, k, v);
  wprep_kernel<<<136, 256, 0, stream>>>(W1, W2, W3, W1f, W2f, W3f);
  gate_kernel<<<E_N, 256, 0, stream>>>(v, Wg1, bg1, Wg2, bg2, gate);
  edge_attn_mfma<<<E_N, 256, 0, stream>>>(ef, coords, q, k, v,
      W1f, W2f, W3f, b1, b2, b3, Wo, bo, gamma, beta, pairs, gate,
      (float*)d_out, (float*)d_out + E_N*HID);
}